// Round 7
// baseline (321.676 us; speedup 1.0000x reference)
//
#include <hip/hip_runtime.h>

// N = 33554432 ; inputs: s (int32 in {0,1}), other_s (int32 in {0,1}), x (float32)
// out = mean( (s==other_s ? 1 : -1) * x )
// R7: R6 (nontemporal loads — the win: bypasses L2/L3 miss-allocation, took
// delivered read from ~3.1 to >5.3 TB/s) + GRID 1024->2048 to double
// outstanding requests/CU now that the regime is latency x MLP governed.

constexpr int BLOCK = 256;
constexpr int GRID  = 2048;   // 8 blocks/CU, 32 waves/CU

typedef int   vi4 __attribute__((ext_vector_type(4)));
typedef float vf4 __attribute__((ext_vector_type(4)));

__global__ __launch_bounds__(BLOCK) void disc_loss_partial(
        const int*   __restrict__ s,
        const int*   __restrict__ o,
        const float* __restrict__ x,
        float*       __restrict__ partials,
        int n4)
{
    const vi4* s4 = (const vi4*)s;
    const vi4* o4 = (const vi4*)o;
    const vf4* x4 = (const vf4*)x;

    float acc = 0.0f;
    const int stride = GRID * BLOCK;   // 524288; n4 = 8388608 -> 16 iters/thread
    for (int i = blockIdx.x * BLOCK + threadIdx.x; i < n4; i += stride) {
        vi4 sv = __builtin_nontemporal_load(&s4[i]);
        vi4 ov = __builtin_nontemporal_load(&o4[i]);
        vf4 xv = __builtin_nontemporal_load(&x4[i]);
        // s,o in {0,1}: flip sign iff s != o  ->  xor sign bit with (s^o)<<31
        vi4 sgn = (sv ^ ov) << 31;
        acc += __int_as_float(__float_as_int(xv.x) ^ sgn.x);
        acc += __int_as_float(__float_as_int(xv.y) ^ sgn.y);
        acc += __int_as_float(__float_as_int(xv.z) ^ sgn.z);
        acc += __int_as_float(__float_as_int(xv.w) ^ sgn.w);
    }

    // wave-64 shuffle reduction
    #pragma unroll
    for (int off = 32; off > 0; off >>= 1)
        acc += __shfl_down(acc, off, 64);

    __shared__ float lds[BLOCK / 64];
    int lane = threadIdx.x & 63;
    int wid  = threadIdx.x >> 6;
    if (lane == 0) lds[wid] = acc;
    __syncthreads();
    if (threadIdx.x == 0) {
        float sum = 0.0f;
        #pragma unroll
        for (int w = 0; w < BLOCK / 64; ++w) sum += lds[w];
        partials[blockIdx.x] = sum;
    }
}

__global__ __launch_bounds__(256) void disc_loss_final(
        const float* __restrict__ partials,
        float*       __restrict__ out,
        float inv_n)
{
    float acc = 0.0f;
    #pragma unroll
    for (int i = threadIdx.x; i < GRID; i += 256)
        acc += partials[i];

    #pragma unroll
    for (int off = 32; off > 0; off >>= 1)
        acc += __shfl_down(acc, off, 64);

    __shared__ float lds[4];
    int lane = threadIdx.x & 63;
    int wid  = threadIdx.x >> 6;
    if (lane == 0) lds[wid] = acc;
    __syncthreads();
    if (threadIdx.x == 0)
        out[0] = (lds[0] + lds[1] + lds[2] + lds[3]) * inv_n;
}

extern "C" void kernel_launch(void* const* d_in, const int* in_sizes, int n_in,
                              void* d_out, int out_size, void* d_ws, size_t ws_size,
                              hipStream_t stream)
{
    const int*   s = (const int*)d_in[0];
    const int*   o = (const int*)d_in[1];
    const float* x = (const float*)d_in[2];
    float* out      = (float*)d_out;
    float* partials = (float*)d_ws;   // GRID floats = 8 KB

    int n  = in_sizes[0];
    int n4 = n / 4;                   // N divisible by 4

    disc_loss_partial<<<GRID, BLOCK, 0, stream>>>(s, o, x, partials, n4);
    disc_loss_final<<<1, 256, 0, stream>>>(partials, out, 1.0f / (float)n);
}